// Round 6
// baseline (233.259 us; speedup 1.0000x reference)
//
#include <hip/hip_runtime.h>
#include <hip/hip_fp16.h>
#include <hip/hip_bf16.h>

#define BATCH  16
#define SEQ    4096
#define DIM    64
#define NHASH  8
#define NCHUNK 512   // chunks per batch row (NHASH * SEQ / 64)
#define SB     72    // bf16 LDS row stride: 72*2=144 B, 16B-aligned for b128

typedef __attribute__((ext_vector_type(8))) short short8;   // 8 bf16 (4 VGPR)
typedef __attribute__((ext_vector_type(4))) float floatx4;  // MFMA C/D

__device__ __forceinline__ float trunc_hi(float a) {
    return __uint_as_float(__float_as_uint(a) & 0xffff0000u);
}
__device__ __forceinline__ unsigned pack_hi2(float a, float b) {
    return (__float_as_uint(a) >> 16) | (__float_as_uint(b) & 0xffff0000u);
}
// 16 fp32 -> 16 bf16 via paired HW cvt (v_cvt_pk_bf16_f32, RNE)
__device__ __forceinline__ void hi16_store_cvt(const float* xs, short* dst) {
    union { __hip_bfloat162 h2[8]; uint4 u4[2]; } U;
#pragma unroll
    for (int u = 0; u < 8; ++u)
        U.h2[u] = __float22bfloat162_rn(make_float2(xs[2*u], xs[2*u + 1]));
    *(uint4*)(dst)     = U.u4[0];
    *(uint4*)(dst + 8) = U.u4[1];
}
// split 8 fp32 -> bf16 hi/lo short8 fragments in registers (exact split: trunc)
__device__ __forceinline__ void split8_frag(const float* xs, short8* hi, short8* lo) {
    union { unsigned u[4]; short8 s; } H, L;
#pragma unroll
    for (int u = 0; u < 4; ++u) {
        float a = xs[2*u], b = xs[2*u + 1];
        H.u[u] = pack_hi2(a, b);
        L.u[u] = pack_hi2(a - trunc_hi(a), b - trunc_hi(b));
    }
    *hi = H.s; *lo = L.s;
}

__device__ __forceinline__ void argmax_store(
    const float* a, int gid, int h, int* __restrict__ buckets)
{
    float best = a[0]; int bi = 0;
#pragma unroll
    for (int i = 1; i < 32; ++i) { if (a[i] > best) { best = a[i]; bi = i; } }
#pragma unroll
    for (int i = 0; i < 32; ++i) { float nv = -a[i]; if (nv > best) { best = nv; bi = i + 32; } }
    int b = gid >> 12, t = gid & 4095;
    buckets[((size_t)b * NHASH + h) * SEQ + t] = bi;
}

// ---------------------------------------------------------------------------
// Kernel 1: LSH hashing. R16: occupancy + pipeline fix. R15 post-mortem: the
// hash is latency-bound (~25% VALU util), not DS-bound -- grid 512 = 2
// blocks/CU = 2 waves/SIMD, and the ft-loop's 8 global q-loads stall each
// iteration. Changes:
//  - tile 128 tokens (grid 1024): threads = 64 tt x 4 hp, 2 tokens x 1 h'
//    per thread. acc 64 + q 16 + prefetch 16 VGPR -> launch_bounds(256,4)
//    => 4 waves/SIMD, 4 blocks/CU (LDS 32 KB x 4 = 128 <= 160 KB),
//    16 waves/CU = 2x the latency hiding.
//  - manual q-prefetch: ft+1's loads issue before ft's FMA block.
// FMA order per (token,h') bitwise identical -> same buckets.
// ---------------------------------------------------------------------------
__global__ __launch_bounds__(256, 4) void lsh_hash_kernel(
    const float* __restrict__ qk, const float* __restrict__ rot,
    int* __restrict__ buckets)
{
    __shared__ float rs[64 * 128];     // [f][h'][i] = f*128 + h'*32 + i (32 KB)
    int tid = threadIdx.x;
    int tb   = blockIdx.x >> 1;        // 128-token tile
    int hsel = blockIdx.x & 1;         // h half: h = hsel*4 + h'

    {   // stage rot slice: 2048 float4, 8 per thread, coalesced
        const float4* rg = (const float4*)rot;
#pragma unroll
        for (int j = 0; j < 8; ++j) {
            int idx4 = j * 256 + tid;
            int f = idx4 >> 5, r4 = idx4 & 31;
            ((float4*)rs)[idx4] = rg[f * 64 + hsel * 32 + r4];
        }
    }
    __syncthreads();

    int tt = tid & 63;
    int hp = tid >> 6;                 // 0..3, wave-uniform
    int gid = tb * 128 + tt;           // tokens gid, gid+64
    const float* rbase = rs + hp * 32;

    const float* q0 = qk + (size_t)gid * DIM;
    const float* q1 = q0 + 64 * DIM;

    float a0[32], a1[32];
#pragma unroll
    for (int i = 0; i < 32; ++i) { a0[i] = 0.f; a1[i] = 0.f; }

    // software-pipelined ft loop: load ft+1's q while computing ft
    float qa[8], qb[8];
    *(float4*)&qa[0] = *(const float4*)(q0);
    *(float4*)&qa[4] = *(const float4*)(q0 + 4);
    *(float4*)&qb[0] = *(const float4*)(q1);
    *(float4*)&qb[4] = *(const float4*)(q1 + 4);

#pragma unroll 1
    for (int ft = 0; ft < 8; ++ft) {
        float na[8], nb[8];
        if (ft < 7) {
            *(float4*)&na[0] = *(const float4*)(q0 + (ft + 1) * 8);
            *(float4*)&na[4] = *(const float4*)(q0 + (ft + 1) * 8 + 4);
            *(float4*)&nb[0] = *(const float4*)(q1 + (ft + 1) * 8);
            *(float4*)&nb[4] = *(const float4*)(q1 + (ft + 1) * 8 + 4);
        }
#pragma unroll
        for (int f8 = 0; f8 < 8; ++f8) {
            const float* rp = rbase + (ft * 8 + f8) * 128;
            float x0 = qa[f8], x1 = qb[f8];
#pragma unroll
            for (int i = 0; i < 32; ++i) {
                float r = rp[i];
                a0[i] = fmaf(x0, r, a0[i]);
                a1[i] = fmaf(x1, r, a1[i]);
            }
        }
#pragma unroll
        for (int u = 0; u < 8; ++u) { qa[u] = na[u]; qb[u] = nb[u]; }
    }

    int h = hsel * 4 + hp;
    argmax_store(a0, gid,      h, buckets);
    argmax_store(a1, gid + 64, h, buckets);
}

// ---------------------------------------------------------------------------
// Kernel 2: stable counting sort per (b,h), 4-wave (unchanged).
// ---------------------------------------------------------------------------
__global__ __launch_bounds__(256) void lsh_sort_kernel(
    const int* __restrict__ buckets, int* __restrict__ st)
{
    __shared__ int hist[256 * 65];
    __shared__ int seg[256];
    __shared__ int base[64];

    int bh = blockIdx.x;
    int tid = threadIdx.x;
    int w = tid >> 6, lane = tid & 63;

    for (int i = tid; i < 256 * 65; i += 256) hist[i] = 0;

    int myb[16];
    {
        const int4* bp4 = (const int4*)(buckets + (size_t)bh * SEQ);
#pragma unroll
        for (int u4 = 0; u4 < 4; ++u4) {
            int4 bb = bp4[tid * 4 + u4];
            myb[u4*4+0] = bb.x; myb[u4*4+1] = bb.y;
            myb[u4*4+2] = bb.z; myb[u4*4+3] = bb.w;
        }
    }
    __syncthreads();
    int* hrow = &hist[tid * 65];
#pragma unroll
    for (int u = 0; u < 16; ++u) hrow[myb[u]] += 1;
    __syncthreads();

    {
        int run = 0;
        for (int tp = 0; tp < 64; ++tp) {
            int idx = (w * 64 + tp) * 65 + lane;
            int c0 = hist[idx];
            hist[idx] = run;
            run += c0;
        }
        seg[w * 64 + lane] = run;
    }
    __syncthreads();
    if (tid < 64) {
        int s0 = seg[lane], s1 = seg[64 + lane], s2 = seg[128 + lane], s3 = seg[192 + lane];
        seg[lane] = 0; seg[64 + lane] = s0;
        seg[128 + lane] = s0 + s1; seg[192 + lane] = s0 + s1 + s2;
        int tot = s0 + s1 + s2 + s3;
        int x = tot;
#pragma unroll
        for (int d = 1; d < 64; d <<= 1) {
            int y = __shfl_up(x, d, 64);
            if (lane >= d) x += y;
        }
        base[lane] = x - tot;
    }
    __syncthreads();

    int* op = st + (size_t)bh * SEQ;
#pragma unroll
    for (int u = 0; u < 16; ++u) {
        int bb = myb[u];
        int local = hrow[bb];
        hrow[bb] = local + 1;
        int pos = base[bb] + seg[w * 64 + bb] + local;
        op[pos] = tid * 16 + u;
    }
}

// ---------------------------------------------------------------------------
// Kernel 3: MFMA attention (unchanged from R15: 5 blocks/CU via 10 KB pad,
// XCD swizzle, P hi-only RN, cvt_pk staging, fp16 Obuf -- 82 us, FETCH 19 MB).
// ---------------------------------------------------------------------------
__global__ __launch_bounds__(256, 5) void lsh_attn_kernel(
    const float* __restrict__ qk, const float* __restrict__ v,
    const int* __restrict__ st, __half* __restrict__ Obuf, float* __restrict__ Dbuf)
{
    __shared__ short Khi[64 * SB];     // staged K-hi; doubles as P-hi after dots
    __shared__ short Vhi[64 * SB];     // transposed: [dim][key], hi only
    __shared__ int   tk[64];
    __shared__ float lds_pad[2560];    // 10 KB occupancy cap: 29.2 KB -> 5 blk/CU

    short* Phi = Khi;

    int tid  = threadIdx.x;
    {   // volatile touch so the pad allocation can't be eliminated
        volatile float* vp = lds_pad;
        vp[tid] = 0.f;
    }
    int lane = tid & 63;
    int w    = tid >> 6;          // wave id = query-strip / V key-group
    int quad = lane >> 4;
    int l15  = lane & 15;

    // XCD-aware chunk assignment: XCD x processes chunks [x*1024, x*1024+1024)
    // = 2 whole batches sequentially (8192 = 8 XCDs * 1024, bijective).
    int B  = blockIdx.x;
    int bc = ((B & 7) << 10) | (B >> 3);
    int b = bc >> 9, c = bc & (NCHUNK - 1);
    int cm = (c + NCHUNK - 1) & (NCHUNK - 1);

    const int*   stb = st + (size_t)b * (NHASH * SEQ);
    const float* qkb = qk + (size_t)b * SEQ * DIM;
    const float* vb  = v  + (size_t)b * SEQ * DIM;

    // ---- Q fragments in registers (both halves use the same Q) ----
    short8 qH[2], qL[2];
    {
        int qt = stb[c * 64 + 16 * w + l15];       // this lane's Q row token
        const float* qp = qkb + (size_t)qt * DIM + 8 * quad;
        float xs[8];
#pragma unroll
        for (int kb = 0; kb < 2; ++kb) {
            *(float4*)&xs[0] = *(const float4*)(qp + 32 * kb);
            *(float4*)&xs[4] = *(const float4*)(qp + 32 * kb + 4);
            split8_frag(xs, &qH[kb], &qL[kb]);
        }
    }
    // mask row-ids for this lane's C-fragment rows (quad*4+r), both halves
    int tqr[4];
#pragma unroll
    for (int r = 0; r < 4; ++r) tqr[r] = stb[c * 64 + 16 * w + quad * 4 + r];

    float   Dacc[4] = {0.f, 0.f, 0.f, 0.f};
    floatx4 oacc[4];
#pragma unroll
    for (int a = 0; a < 4; ++a) oacc[a] = (floatx4){0.f, 0.f, 0.f, 0.f};

    for (int half = 0; half < 2; ++half) {
        int ck = half ? cm : c;
        __syncthreads();              // prev-half P/V LDS reads complete

        {   // stage K (L2-normalized, hi-only RNE): 4 threads/row, 16 dims each
            int r = tid >> 2, s = tid & 3;
            int trow = stb[ck * 64 + r];
            if (s == 0) tk[r] = trow;
            const float4* k4 = (const float4*)(qkb + (size_t)trow * DIM + s * 16);
            float xs[16];
            *(float4*)&xs[0]  = k4[0];
            *(float4*)&xs[4]  = k4[1];
            *(float4*)&xs[8]  = k4[2];
            *(float4*)&xs[12] = k4[3];
            float ss = 0.f;
#pragma unroll
            for (int u = 0; u < 16; ++u) ss += xs[u] * xs[u];
            ss += __shfl_xor(ss, 1);
            ss += __shfl_xor(ss, 2);
            float sc = 1.0f / fmaxf(sqrtf(ss), 1e-12f);
#pragma unroll
            for (int u = 0; u < 16; ++u) xs[u] *= sc;
            hi16_store_cvt(xs, &Khi[r * SB + s * 16]);
        }
        {   // stage V TRANSPOSED (hi-only RNE): thread = dim lane, keys w*16..+15
            float xs[16];
#pragma unroll
            for (int u = 0; u < 16; ++u) {
                int trow = stb[ck * 64 + w * 16 + u];     // wave-uniform
                xs[u] = vb[(size_t)trow * DIM + lane];    // coalesced 256B row
            }
            hi16_store_cvt(xs, &Vhi[lane * SB + w * 16]);
        }
        __syncthreads();              // K, Vt, tk staged

        // dots: dt = q · K_hi^T  (2-term split: (qH+qL)*kH)
        floatx4 dt[4];
#pragma unroll
        for (int jt = 0; jt < 4; ++jt) dt[jt] = (floatx4){0.f, 0.f, 0.f, 0.f};
#pragma unroll
        for (int kb = 0; kb < 2; ++kb) {
#pragma unroll
            for (int jt = 0; jt < 4; ++jt) {
                short8 bH = *(const short8*)&Khi[(16 * jt + l15) * SB + kb * 32 + quad * 8];
                dt[jt] = __builtin_amdgcn_mfma_f32_16x16x32_bf16(qH[kb], bH, dt[jt], 0, 0, 0);
                dt[jt] = __builtin_amdgcn_mfma_f32_16x16x32_bf16(qL[kb], bH, dt[jt], 0, 0, 0);
            }
        }
        __syncthreads();              // all dots reads of K done -> P may overwrite

        // mask + exp (fp32) + wave-private P-hi write (half-up) + denom partials
#pragma unroll
        for (int jt = 0; jt < 4; ++jt) {
            int tkc = tk[16 * jt + l15];
#pragma unroll
            for (int r = 0; r < 4; ++r) {
                float p = (tqr[r] == tkc) ? 0.f : __expf(dt[jt][r] * 0.125f);
                Dacc[r] += p;
                int idx = (16 * w + quad * 4 + r) * SB + 16 * jt + l15;
                Phi[idx] = (short)((__float_as_uint(p) + 0x8000u) >> 16);
            }
        }

        // PV: O += P_hi·V_hi (A = own P strip -> no barrier; B = Vt hi)
#pragma unroll
        for (int kb = 0; kb < 2; ++kb) {
            short8 aH = *(const short8*)&Phi[(16 * w + l15) * SB + kb * 32 + quad * 8];
#pragma unroll
            for (int a = 0; a < 4; ++a) {
                short8 bH = *(const short8*)&Vhi[(16 * a + l15) * SB + kb * 32 + quad * 8];
                oacc[a] = __builtin_amdgcn_mfma_f32_16x16x32_bf16(aH, bH, oacc[a], 0, 0, 0);
            }
        }
    }

    // epilogue: scatter to token-major rows Obuf[((b*4096+t)*8 + h)*64 + d]
    // in fp16 (halved round-trip), h = c>>6.
    int h = c >> 6;
#pragma unroll
    for (int r = 0; r < 4; ++r) {
        int t = tqr[r];
        size_t rowb = ((size_t)(b * SEQ + t) * NHASH + h) * DIM;
#pragma unroll
        for (int a = 0; a < 4; ++a)
            Obuf[rowb + 16 * a + l15] = __float2half(oacc[a][r]);
    }
#pragma unroll
    for (int r = 0; r < 4; ++r) {
        float rs = Dacc[r];
        rs += __shfl_xor(rs, 1);
        rs += __shfl_xor(rs, 2);
        rs += __shfl_xor(rs, 4);
        rs += __shfl_xor(rs, 8);
        if (l15 == 0) Dbuf[(size_t)(b * SEQ + tqr[r]) * NHASH + h] = rs;
    }
}

// ---------------------------------------------------------------------------
// Kernel 4: out[b,t] = sum_h O_h / sum_h D_h -- streaming, fp16 numerator.
// Traffic: read 67 MB (Obuf) + 2 MB (Dbuf), write 16.8 MB.
// ---------------------------------------------------------------------------
__global__ __launch_bounds__(256) void lsh_combine_tok(
    const __half* __restrict__ Obuf, const float* __restrict__ Dbuf,
    float* __restrict__ out)
{
    int gid = blockIdx.x * 256 + threadIdx.x;   // (b*4096+t)*16 + d4
    int d4 = gid & 15;
    int bt = gid >> 4;

    const __half* op = Obuf + (size_t)bt * (NHASH * DIM) + d4 * 4;
    const float*  dp = Dbuf + (size_t)bt * NHASH;

    float4 n = make_float4(0.f, 0.f, 0.f, 0.f);
    float den = 0.f;
#pragma unroll
    for (int h = 0; h < NHASH; ++h) {
        uint2 u = *(const uint2*)(op + h * DIM);
        __half2 p01 = *(__half2*)&u.x;
        __half2 p23 = *(__half2*)&u.y;
        float2 f01 = __half22float2(p01);
        float2 f23 = __half22float2(p23);
        den += dp[h];
        n.x += f01.x; n.y += f01.y; n.z += f23.x; n.w += f23.y;
    }
    float invd = 1.0f / den;
    float4 r; r.x = n.x*invd; r.y = n.y*invd; r.z = n.z*invd; r.w = n.w*invd;
    ((float4*)out)[gid] = r;
}

extern "C" void kernel_launch(void* const* d_in, const int* in_sizes, int n_in,
                              void* d_out, int out_size, void* d_ws, size_t ws_size,
                              hipStream_t stream)
{
    const float* qk  = (const float*)d_in[0];
    const float* v   = (const float*)d_in[1];
    const float* rot = (const float*)d_in[2];
    float* out = (float*)d_out;

    char* w = (char*)d_ws;
    // workspace layout (73.2 MB):
    //   [0, 2MB)          buckets : int[16*8*4096]
    //   [2, 4MB)          st      : int[16*8*4096]
    //   [4MB, +67.1MB)    Obuf    : fp16[16*4096*8*64]  (token-major, h inner)
    //   then              Dbuf    : fp32[16*4096*8]
    int*    buckets = (int*)(w);
    int*    st      = (int*)(w + 2097152);
    __half* Obuf    = (__half*)(w + 4194304);
    float*  Dbuf    = (float*)(w + 4194304 + 67108864);

    lsh_hash_kernel<<<1024, 256, 0, stream>>>(qk, rot, buckets);
    lsh_sort_kernel<<<128, 256, 0, stream>>>(buckets, st);
    lsh_attn_kernel<<<8192, 256, 0, stream>>>(qk, v, st, Obuf, Dbuf);
    lsh_combine_tok<<<4096, 256, 0, stream>>>(Obuf, Dbuf, out);
}

// Round 7
// 201.413 us; speedup vs baseline: 1.1581x; 1.1581x over previous
//
#include <hip/hip_runtime.h>
#include <hip/hip_fp16.h>
#include <hip/hip_bf16.h>

#define BATCH  16
#define SEQ    4096
#define DIM    64
#define NHASH  8
#define NCHUNK 512   // chunks per batch row (NHASH * SEQ / 64)
#define SB     72    // bf16 LDS row stride: 72*2=144 B, 16B-aligned for b128

typedef __attribute__((ext_vector_type(8))) short short8;   // 8 bf16 (4 VGPR)
typedef __attribute__((ext_vector_type(4))) float floatx4;  // MFMA C/D

__device__ __forceinline__ float trunc_hi(float a) {
    return __uint_as_float(__float_as_uint(a) & 0xffff0000u);
}
__device__ __forceinline__ unsigned pack_hi2(float a, float b) {
    return (__float_as_uint(a) >> 16) | (__float_as_uint(b) & 0xffff0000u);
}
// 16 fp32 -> 16 bf16 via paired HW cvt (v_cvt_pk_bf16_f32, RNE)
__device__ __forceinline__ void hi16_store_cvt(const float* xs, short* dst) {
    union { __hip_bfloat162 h2[8]; uint4 u4[2]; } U;
#pragma unroll
    for (int u = 0; u < 8; ++u)
        U.h2[u] = __float22bfloat162_rn(make_float2(xs[2*u], xs[2*u + 1]));
    *(uint4*)(dst)     = U.u4[0];
    *(uint4*)(dst + 8) = U.u4[1];
}
// split 8 fp32 -> bf16 hi/lo short8 fragments in registers (exact split: trunc)
__device__ __forceinline__ void split8_frag(const float* xs, short8* hi, short8* lo) {
    union { unsigned u[4]; short8 s; } H, L;
#pragma unroll
    for (int u = 0; u < 4; ++u) {
        float a = xs[2*u], b = xs[2*u + 1];
        H.u[u] = pack_hi2(a, b);
        L.u[u] = pack_hi2(a - trunc_hi(a), b - trunc_hi(b));
    }
    *hi = H.s; *lo = L.s;
}

__device__ __forceinline__ void argmax_store(
    const float* a, int gid, int h, int* __restrict__ buckets)
{
    float best = a[0]; int bi = 0;
#pragma unroll
    for (int i = 1; i < 32; ++i) { if (a[i] > best) { best = a[i]; bi = i; } }
#pragma unroll
    for (int i = 0; i < 32; ++i) { float nv = -a[i]; if (nv > best) { best = nv; bi = i + 32; } }
    int b = gid >> 12, t = gid & 4095;
    buckets[((size_t)b * NHASH + h) * SEQ + t] = bi;
}

// ---------------------------------------------------------------------------
// Kernel 1: LSH hashing. R17: clean occupancy experiment. R16 post-mortem:
// the (256,4) cap + prefetch arrays (~126-140 VGPR need) spilled -> +30 us.
// This round: grid 512 -> 1024 by halving per-block h-coverage (2 h' per
// block, 16 KB rot slice). Thread = 2 tokens x 1 h' -- register recipe is
// R14's proven ~110 VGPR (NO prefetch arrays) -> fits the 128 cap with
// headroom, no spill. 4 blocks/CU = 16 waves/CU (2x latency hiding vs the
// grid-bound 2 blocks/CU). FMA order per (token,h') bitwise identical.
// ---------------------------------------------------------------------------
__global__ __launch_bounds__(256, 4) void lsh_hash_kernel(
    const float* __restrict__ qk, const float* __restrict__ rot,
    int* __restrict__ buckets)
{
    __shared__ float rs[64 * 64];      // [f][h'][i] = f*64 + hh*32 + i (16 KB)
    int tid = threadIdx.x;
    int tb   = blockIdx.x >> 2;        // 256-token tile
    int hsel = blockIdx.x & 3;         // h pair: h = hsel*2 + hh

    {   // stage rot slice: 1024 float4, 4 per thread, coalesced
        const float4* rg = (const float4*)rot;
#pragma unroll
        for (int j = 0; j < 4; ++j) {
            int idx4 = j * 256 + tid;
            int f = idx4 >> 4, r4 = idx4 & 15;     // r4 = hh*8 + i4
            ((float4*)rs)[idx4] = rg[f * 64 + hsel * 16 + r4];
        }
    }
    __syncthreads();

    int tt = tid & 127;
    int hh = tid >> 7;                 // 0/1, wave-uniform
    int gid0 = tb * 256 + tt;
    int gid1 = gid0 + 128;
    const float* q0 = qk + (size_t)gid0 * DIM;
    const float* q1 = qk + (size_t)gid1 * DIM;
    const float* rbase = rs + hh * 32;

    float a0[32], a1[32];
#pragma unroll
    for (int i = 0; i < 32; ++i) { a0[i] = 0.f; a1[i] = 0.f; }

#pragma unroll 1
    for (int ft = 0; ft < 8; ++ft) {
        float qa[8], qb[8];
        *(float4*)&qa[0] = *(const float4*)(q0 + ft * 8);
        *(float4*)&qa[4] = *(const float4*)(q0 + ft * 8 + 4);
        *(float4*)&qb[0] = *(const float4*)(q1 + ft * 8);
        *(float4*)&qb[4] = *(const float4*)(q1 + ft * 8 + 4);
#pragma unroll
        for (int f8 = 0; f8 < 8; ++f8) {
            const float* rp = rbase + (ft * 8 + f8) * 64;
            float x0 = qa[f8], x1 = qb[f8];
#pragma unroll
            for (int i = 0; i < 32; ++i) {
                float r = rp[i];
                a0[i] = fmaf(x0, r, a0[i]);
                a1[i] = fmaf(x1, r, a1[i]);
            }
        }
    }

    int h = hsel * 2 + hh;
    argmax_store(a0, gid0, h, buckets);
    argmax_store(a1, gid1, h, buckets);
}

// ---------------------------------------------------------------------------
// Kernel 2: stable counting sort per (b,h), 4-wave (unchanged).
// ---------------------------------------------------------------------------
__global__ __launch_bounds__(256) void lsh_sort_kernel(
    const int* __restrict__ buckets, int* __restrict__ st)
{
    __shared__ int hist[256 * 65];
    __shared__ int seg[256];
    __shared__ int base[64];

    int bh = blockIdx.x;
    int tid = threadIdx.x;
    int w = tid >> 6, lane = tid & 63;

    for (int i = tid; i < 256 * 65; i += 256) hist[i] = 0;

    int myb[16];
    {
        const int4* bp4 = (const int4*)(buckets + (size_t)bh * SEQ);
#pragma unroll
        for (int u4 = 0; u4 < 4; ++u4) {
            int4 bb = bp4[tid * 4 + u4];
            myb[u4*4+0] = bb.x; myb[u4*4+1] = bb.y;
            myb[u4*4+2] = bb.z; myb[u4*4+3] = bb.w;
        }
    }
    __syncthreads();
    int* hrow = &hist[tid * 65];
#pragma unroll
    for (int u = 0; u < 16; ++u) hrow[myb[u]] += 1;
    __syncthreads();

    {
        int run = 0;
        for (int tp = 0; tp < 64; ++tp) {
            int idx = (w * 64 + tp) * 65 + lane;
            int c0 = hist[idx];
            hist[idx] = run;
            run += c0;
        }
        seg[w * 64 + lane] = run;
    }
    __syncthreads();
    if (tid < 64) {
        int s0 = seg[lane], s1 = seg[64 + lane], s2 = seg[128 + lane], s3 = seg[192 + lane];
        seg[lane] = 0; seg[64 + lane] = s0;
        seg[128 + lane] = s0 + s1; seg[192 + lane] = s0 + s1 + s2;
        int tot = s0 + s1 + s2 + s3;
        int x = tot;
#pragma unroll
        for (int d = 1; d < 64; d <<= 1) {
            int y = __shfl_up(x, d, 64);
            if (lane >= d) x += y;
        }
        base[lane] = x - tot;
    }
    __syncthreads();

    int* op = st + (size_t)bh * SEQ;
#pragma unroll
    for (int u = 0; u < 16; ++u) {
        int bb = myb[u];
        int local = hrow[bb];
        hrow[bb] = local + 1;
        int pos = base[bb] + seg[w * 64 + bb] + local;
        op[pos] = tid * 16 + u;
    }
}

// ---------------------------------------------------------------------------
// Kernel 3: MFMA attention (unchanged: 5 blocks/CU via 10 KB pad, XCD
// swizzle, P hi-only RN, cvt_pk staging, fp16 Obuf -- 82 us, FETCH 19 MB).
// ---------------------------------------------------------------------------
__global__ __launch_bounds__(256, 5) void lsh_attn_kernel(
    const float* __restrict__ qk, const float* __restrict__ v,
    const int* __restrict__ st, __half* __restrict__ Obuf, float* __restrict__ Dbuf)
{
    __shared__ short Khi[64 * SB];     // staged K-hi; doubles as P-hi after dots
    __shared__ short Vhi[64 * SB];     // transposed: [dim][key], hi only
    __shared__ int   tk[64];
    __shared__ float lds_pad[2560];    // 10 KB occupancy cap: 29.2 KB -> 5 blk/CU

    short* Phi = Khi;

    int tid  = threadIdx.x;
    {   // volatile touch so the pad allocation can't be eliminated
        volatile float* vp = lds_pad;
        vp[tid] = 0.f;
    }
    int lane = tid & 63;
    int w    = tid >> 6;          // wave id = query-strip / V key-group
    int quad = lane >> 4;
    int l15  = lane & 15;

    // XCD-aware chunk assignment: XCD x processes chunks [x*1024, x*1024+1024)
    // = 2 whole batches sequentially (8192 = 8 XCDs * 1024, bijective).
    int B  = blockIdx.x;
    int bc = ((B & 7) << 10) | (B >> 3);
    int b = bc >> 9, c = bc & (NCHUNK - 1);
    int cm = (c + NCHUNK - 1) & (NCHUNK - 1);

    const int*   stb = st + (size_t)b * (NHASH * SEQ);
    const float* qkb = qk + (size_t)b * SEQ * DIM;
    const float* vb  = v  + (size_t)b * SEQ * DIM;

    // ---- Q fragments in registers (both halves use the same Q) ----
    short8 qH[2], qL[2];
    {
        int qt = stb[c * 64 + 16 * w + l15];       // this lane's Q row token
        const float* qp = qkb + (size_t)qt * DIM + 8 * quad;
        float xs[8];
#pragma unroll
        for (int kb = 0; kb < 2; ++kb) {
            *(float4*)&xs[0] = *(const float4*)(qp + 32 * kb);
            *(float4*)&xs[4] = *(const float4*)(qp + 32 * kb + 4);
            split8_frag(xs, &qH[kb], &qL[kb]);
        }
    }
    // mask row-ids for this lane's C-fragment rows (quad*4+r), both halves
    int tqr[4];
#pragma unroll
    for (int r = 0; r < 4; ++r) tqr[r] = stb[c * 64 + 16 * w + quad * 4 + r];

    float   Dacc[4] = {0.f, 0.f, 0.f, 0.f};
    floatx4 oacc[4];
#pragma unroll
    for (int a = 0; a < 4; ++a) oacc[a] = (floatx4){0.f, 0.f, 0.f, 0.f};

    for (int half = 0; half < 2; ++half) {
        int ck = half ? cm : c;
        __syncthreads();              // prev-half P/V LDS reads complete

        {   // stage K (L2-normalized, hi-only RNE): 4 threads/row, 16 dims each
            int r = tid >> 2, s = tid & 3;
            int trow = stb[ck * 64 + r];
            if (s == 0) tk[r] = trow;
            const float4* k4 = (const float4*)(qkb + (size_t)trow * DIM + s * 16);
            float xs[16];
            *(float4*)&xs[0]  = k4[0];
            *(float4*)&xs[4]  = k4[1];
            *(float4*)&xs[8]  = k4[2];
            *(float4*)&xs[12] = k4[3];
            float ss = 0.f;
#pragma unroll
            for (int u = 0; u < 16; ++u) ss += xs[u] * xs[u];
            ss += __shfl_xor(ss, 1);
            ss += __shfl_xor(ss, 2);
            float sc = 1.0f / fmaxf(sqrtf(ss), 1e-12f);
#pragma unroll
            for (int u = 0; u < 16; ++u) xs[u] *= sc;
            hi16_store_cvt(xs, &Khi[r * SB + s * 16]);
        }
        {   // stage V TRANSPOSED (hi-only RNE): thread = dim lane, keys w*16..+15
            float xs[16];
#pragma unroll
            for (int u = 0; u < 16; ++u) {
                int trow = stb[ck * 64 + w * 16 + u];     // wave-uniform
                xs[u] = vb[(size_t)trow * DIM + lane];    // coalesced 256B row
            }
            hi16_store_cvt(xs, &Vhi[lane * SB + w * 16]);
        }
        __syncthreads();              // K, Vt, tk staged

        // dots: dt = q · K_hi^T  (2-term split: (qH+qL)*kH)
        floatx4 dt[4];
#pragma unroll
        for (int jt = 0; jt < 4; ++jt) dt[jt] = (floatx4){0.f, 0.f, 0.f, 0.f};
#pragma unroll
        for (int kb = 0; kb < 2; ++kb) {
#pragma unroll
            for (int jt = 0; jt < 4; ++jt) {
                short8 bH = *(const short8*)&Khi[(16 * jt + l15) * SB + kb * 32 + quad * 8];
                dt[jt] = __builtin_amdgcn_mfma_f32_16x16x32_bf16(qH[kb], bH, dt[jt], 0, 0, 0);
                dt[jt] = __builtin_amdgcn_mfma_f32_16x16x32_bf16(qL[kb], bH, dt[jt], 0, 0, 0);
            }
        }
        __syncthreads();              // all dots reads of K done -> P may overwrite

        // mask + exp (fp32) + wave-private P-hi write (half-up) + denom partials
#pragma unroll
        for (int jt = 0; jt < 4; ++jt) {
            int tkc = tk[16 * jt + l15];
#pragma unroll
            for (int r = 0; r < 4; ++r) {
                float p = (tqr[r] == tkc) ? 0.f : __expf(dt[jt][r] * 0.125f);
                Dacc[r] += p;
                int idx = (16 * w + quad * 4 + r) * SB + 16 * jt + l15;
                Phi[idx] = (short)((__float_as_uint(p) + 0x8000u) >> 16);
            }
        }

        // PV: O += P_hi·V_hi (A = own P strip -> no barrier; B = Vt hi)
#pragma unroll
        for (int kb = 0; kb < 2; ++kb) {
            short8 aH = *(const short8*)&Phi[(16 * w + l15) * SB + kb * 32 + quad * 8];
#pragma unroll
            for (int a = 0; a < 4; ++a) {
                short8 bH = *(const short8*)&Vhi[(16 * a + l15) * SB + kb * 32 + quad * 8];
                oacc[a] = __builtin_amdgcn_mfma_f32_16x16x32_bf16(aH, bH, oacc[a], 0, 0, 0);
            }
        }
    }

    // epilogue: scatter to token-major rows Obuf[((b*4096+t)*8 + h)*64 + d]
    // in fp16 (halved round-trip), h = c>>6.
    int h = c >> 6;
#pragma unroll
    for (int r = 0; r < 4; ++r) {
        int t = tqr[r];
        size_t rowb = ((size_t)(b * SEQ + t) * NHASH + h) * DIM;
#pragma unroll
        for (int a = 0; a < 4; ++a)
            Obuf[rowb + 16 * a + l15] = __float2half(oacc[a][r]);
    }
#pragma unroll
    for (int r = 0; r < 4; ++r) {
        float rs = Dacc[r];
        rs += __shfl_xor(rs, 1);
        rs += __shfl_xor(rs, 2);
        rs += __shfl_xor(rs, 4);
        rs += __shfl_xor(rs, 8);
        if (l15 == 0) Dbuf[(size_t)(b * SEQ + tqr[r]) * NHASH + h] = rs;
    }
}

// ---------------------------------------------------------------------------
// Kernel 4: out[b,t] = sum_h O_h / sum_h D_h -- streaming, fp16 numerator.
// Traffic: read 67 MB (Obuf) + 2 MB (Dbuf), write 16.8 MB.
// ---------------------------------------------------------------------------
__global__ __launch_bounds__(256) void lsh_combine_tok(
    const __half* __restrict__ Obuf, const float* __restrict__ Dbuf,
    float* __restrict__ out)
{
    int gid = blockIdx.x * 256 + threadIdx.x;   // (b*4096+t)*16 + d4
    int d4 = gid & 15;
    int bt = gid >> 4;

    const __half* op = Obuf + (size_t)bt * (NHASH * DIM) + d4 * 4;
    const float*  dp = Dbuf + (size_t)bt * NHASH;

    float4 n = make_float4(0.f, 0.f, 0.f, 0.f);
    float den = 0.f;
#pragma unroll
    for (int h = 0; h < NHASH; ++h) {
        uint2 u = *(const uint2*)(op + h * DIM);
        __half2 p01 = *(__half2*)&u.x;
        __half2 p23 = *(__half2*)&u.y;
        float2 f01 = __half22float2(p01);
        float2 f23 = __half22float2(p23);
        den += dp[h];
        n.x += f01.x; n.y += f01.y; n.z += f23.x; n.w += f23.y;
    }
    float invd = 1.0f / den;
    float4 r; r.x = n.x*invd; r.y = n.y*invd; r.z = n.z*invd; r.w = n.w*invd;
    ((float4*)out)[gid] = r;
}

extern "C" void kernel_launch(void* const* d_in, const int* in_sizes, int n_in,
                              void* d_out, int out_size, void* d_ws, size_t ws_size,
                              hipStream_t stream)
{
    const float* qk  = (const float*)d_in[0];
    const float* v   = (const float*)d_in[1];
    const float* rot = (const float*)d_in[2];
    float* out = (float*)d_out;

    char* w = (char*)d_ws;
    // workspace layout (73.2 MB):
    //   [0, 2MB)          buckets : int[16*8*4096]
    //   [2, 4MB)          st      : int[16*8*4096]
    //   [4MB, +67.1MB)    Obuf    : fp16[16*4096*8*64]  (token-major, h inner)
    //   then              Dbuf    : fp32[16*4096*8]
    int*    buckets = (int*)(w);
    int*    st      = (int*)(w + 2097152);
    __half* Obuf    = (__half*)(w + 4194304);
    float*  Dbuf    = (float*)(w + 4194304 + 67108864);

    lsh_hash_kernel<<<1024, 256, 0, stream>>>(qk, rot, buckets);
    lsh_sort_kernel<<<128, 256, 0, stream>>>(buckets, st);
    lsh_attn_kernel<<<8192, 256, 0, stream>>>(qk, v, st, Obuf, Dbuf);
    lsh_combine_tok<<<4096, 256, 0, stream>>>(Obuf, Dbuf, out);
}

// Round 8
// 198.503 us; speedup vs baseline: 1.1751x; 1.0147x over previous
//
#include <hip/hip_runtime.h>
#include <hip/hip_fp16.h>
#include <hip/hip_bf16.h>

#define BATCH  16
#define SEQ    4096
#define DIM    64
#define NHASH  8
#define NCHUNK 512   // chunks per batch row (NHASH * SEQ / 64)
#define SB     72    // bf16 LDS row stride: 72*2=144 B, 16B-aligned for b128

typedef __attribute__((ext_vector_type(8))) short short8;   // 8 bf16 (4 VGPR)
typedef __attribute__((ext_vector_type(4))) float floatx4;  // MFMA C/D

// 16 fp32 -> 16 bf16 via paired HW cvt (v_cvt_pk_bf16_f32, RNE)
__device__ __forceinline__ void hi16_store_cvt(const float* xs, short* dst) {
    union { __hip_bfloat162 h2[8]; uint4 u4[2]; } U;
#pragma unroll
    for (int u = 0; u < 8; ++u)
        U.h2[u] = __float22bfloat162_rn(make_float2(xs[2*u], xs[2*u + 1]));
    *(uint4*)(dst)     = U.u4[0];
    *(uint4*)(dst + 8) = U.u4[1];
}
__device__ __forceinline__ unsigned pk_bf16(float a, float b) {
    union { __hip_bfloat162 h2; unsigned u; } U;
    U.h2 = __float22bfloat162_rn(make_float2(a, b));
    return U.u;
}

__device__ __forceinline__ void argmax_store(
    const float* a, int gid, int h, int* __restrict__ buckets)
{
    float best = a[0]; int bi = 0;
#pragma unroll
    for (int i = 1; i < 32; ++i) { if (a[i] > best) { best = a[i]; bi = i; } }
#pragma unroll
    for (int i = 0; i < 32; ++i) { float nv = -a[i]; if (nv > best) { best = nv; bi = i + 32; } }
    int b = gid >> 12, t = gid & 4095;
    buckets[((size_t)b * NHASH + h) * SEQ + t] = bi;
}

// ---------------------------------------------------------------------------
// Kernel 1: LSH hashing (R17 config: grid 1024, 2 h'/block, 16 KB rot LDS,
// 4 blocks/CU, no spill). Proven at the ~201 us total; near its VALU floor.
// ---------------------------------------------------------------------------
__global__ __launch_bounds__(256, 4) void lsh_hash_kernel(
    const float* __restrict__ qk, const float* __restrict__ rot,
    int* __restrict__ buckets)
{
    __shared__ float rs[64 * 64];      // [f][h'][i] = f*64 + hh*32 + i (16 KB)
    int tid = threadIdx.x;
    int tb   = blockIdx.x >> 2;        // 256-token tile
    int hsel = blockIdx.x & 3;         // h pair: h = hsel*2 + hh

    {   // stage rot slice: 1024 float4, 4 per thread, coalesced
        const float4* rg = (const float4*)rot;
#pragma unroll
        for (int j = 0; j < 4; ++j) {
            int idx4 = j * 256 + tid;
            int f = idx4 >> 4, r4 = idx4 & 15;     // r4 = hh*8 + i4
            ((float4*)rs)[idx4] = rg[f * 64 + hsel * 16 + r4];
        }
    }
    __syncthreads();

    int tt = tid & 127;
    int hh = tid >> 7;                 // 0/1, wave-uniform
    int gid0 = tb * 256 + tt;
    int gid1 = gid0 + 128;
    const float* q0 = qk + (size_t)gid0 * DIM;
    const float* q1 = qk + (size_t)gid1 * DIM;
    const float* rbase = rs + hh * 32;

    float a0[32], a1[32];
#pragma unroll
    for (int i = 0; i < 32; ++i) { a0[i] = 0.f; a1[i] = 0.f; }

#pragma unroll 1
    for (int ft = 0; ft < 8; ++ft) {
        float qa[8], qb[8];
        *(float4*)&qa[0] = *(const float4*)(q0 + ft * 8);
        *(float4*)&qa[4] = *(const float4*)(q0 + ft * 8 + 4);
        *(float4*)&qb[0] = *(const float4*)(q1 + ft * 8);
        *(float4*)&qb[4] = *(const float4*)(q1 + ft * 8 + 4);
#pragma unroll
        for (int f8 = 0; f8 < 8; ++f8) {
            const float* rp = rbase + (ft * 8 + f8) * 64;
            float x0 = qa[f8], x1 = qb[f8];
#pragma unroll
            for (int i = 0; i < 32; ++i) {
                float r = rp[i];
                a0[i] = fmaf(x0, r, a0[i]);
                a1[i] = fmaf(x1, r, a1[i]);
            }
        }
    }

    int h = hsel * 2 + hh;
    argmax_store(a0, gid0, h, buckets);
    argmax_store(a1, gid1, h, buckets);
}

// ---------------------------------------------------------------------------
// Kernel 2: stable counting sort per (b,h), 4-wave (unchanged).
// ---------------------------------------------------------------------------
__global__ __launch_bounds__(256) void lsh_sort_kernel(
    const int* __restrict__ buckets, int* __restrict__ st)
{
    __shared__ int hist[256 * 65];
    __shared__ int seg[256];
    __shared__ int base[64];

    int bh = blockIdx.x;
    int tid = threadIdx.x;
    int w = tid >> 6, lane = tid & 63;

    for (int i = tid; i < 256 * 65; i += 256) hist[i] = 0;

    int myb[16];
    {
        const int4* bp4 = (const int4*)(buckets + (size_t)bh * SEQ);
#pragma unroll
        for (int u4 = 0; u4 < 4; ++u4) {
            int4 bb = bp4[tid * 4 + u4];
            myb[u4*4+0] = bb.x; myb[u4*4+1] = bb.y;
            myb[u4*4+2] = bb.z; myb[u4*4+3] = bb.w;
        }
    }
    __syncthreads();
    int* hrow = &hist[tid * 65];
#pragma unroll
    for (int u = 0; u < 16; ++u) hrow[myb[u]] += 1;
    __syncthreads();

    {
        int run = 0;
        for (int tp = 0; tp < 64; ++tp) {
            int idx = (w * 64 + tp) * 65 + lane;
            int c0 = hist[idx];
            hist[idx] = run;
            run += c0;
        }
        seg[w * 64 + lane] = run;
    }
    __syncthreads();
    if (tid < 64) {
        int s0 = seg[lane], s1 = seg[64 + lane], s2 = seg[128 + lane], s3 = seg[192 + lane];
        seg[lane] = 0; seg[64 + lane] = s0;
        seg[128 + lane] = s0 + s1; seg[192 + lane] = s0 + s1 + s2;
        int tot = s0 + s1 + s2 + s3;
        int x = tot;
#pragma unroll
        for (int d = 1; d < 64; d <<= 1) {
            int y = __shfl_up(x, d, 64);
            if (lane >= d) x += y;
        }
        base[lane] = x - tot;
    }
    __syncthreads();

    int* op = st + (size_t)bh * SEQ;
#pragma unroll
    for (int u = 0; u < 16; ++u) {
        int bb = myb[u];
        int local = hrow[bb];
        hrow[bb] = local + 1;
        int pos = base[bb] + seg[w * 64 + bb] + local;
        op[pos] = tid * 16 + u;
    }
}

// ---------------------------------------------------------------------------
// Kernel 3: MFMA attention. R18: swapped QK^T (T12 pattern) -- dots =
// mfma(K, Q) puts query on the C col (=l15), so each wave holds its full
// P strip in registers. P->LDS round-trip (16 ds_write_b16 + 2 ds_read_b128
// + 48 pack VALU per half) replaced by 8 cvt_pk + 16 bpermute + 8 selects;
// the post-dots barrier is deleted (3->2 barriers/half). Q is hi-only RNE
// now (R10's K-lo argument: ~1e-4 output impact), halving dots MFMAs.
// Keeps: 5 blocks/CU via pad, XCD swizzle, fp16 Obuf, cvt_pk staging.
// ---------------------------------------------------------------------------
__global__ __launch_bounds__(256, 5) void lsh_attn_kernel(
    const float* __restrict__ qk, const float* __restrict__ v,
    const int* __restrict__ st, __half* __restrict__ Obuf, float* __restrict__ Dbuf)
{
    __shared__ short Khi[64 * SB];     // staged K-hi (L2-normalized)
    __shared__ short Vhi[64 * SB];     // transposed: [dim][key], hi only
    __shared__ int   tk[64];
    __shared__ float lds_pad[2560];    // 10 KB occupancy cap: 29.2 KB -> 5 blk/CU

    int tid  = threadIdx.x;
    {   // volatile touch so the pad allocation can't be eliminated
        volatile float* vp = lds_pad;
        vp[tid] = 0.f;
    }
    int lane = tid & 63;
    int w    = tid >> 6;          // wave id = query-strip / V key-group
    int quad = lane >> 4;
    int l15  = lane & 15;

    // XCD-aware chunk assignment: XCD x processes chunks [x*1024, x*1024+1024)
    // = 2 whole batches sequentially (8192 = 8 XCDs * 1024, bijective).
    int B  = blockIdx.x;
    int bc = ((B & 7) << 10) | (B >> 3);
    int b = bc >> 9, c = bc & (NCHUNK - 1);
    int cm = (c + NCHUNK - 1) & (NCHUNK - 1);

    const int*   stb = st + (size_t)b * (NHASH * SEQ);
    const float* qkb = qk + (size_t)b * SEQ * DIM;
    const float* vb  = v  + (size_t)b * SEQ * DIM;

    // ---- Q fragment (hi-only RNE) in registers; qt = this lane's Q token ----
    short8 qH[2];
    int qt;
    {
        qt = stb[c * 64 + 16 * w + l15];
        const float* qp = qkb + (size_t)qt * DIM + 8 * quad;
#pragma unroll
        for (int kb = 0; kb < 2; ++kb) {
            float xs[8];
            *(float4*)&xs[0] = *(const float4*)(qp + 32 * kb);
            *(float4*)&xs[4] = *(const float4*)(qp + 32 * kb + 4);
            union { __hip_bfloat162 h2[4]; short8 s; } Uq;
#pragma unroll
            for (int u = 0; u < 4; ++u)
                Uq.h2[u] = __float22bfloat162_rn(make_float2(xs[2*u], xs[2*u + 1]));
            qH[kb] = Uq.s;
        }
    }
    // epilogue row-ids for this lane's O fragment rows (quad*4+r)
    int tqr[4];
#pragma unroll
    for (int r = 0; r < 4; ++r) tqr[r] = stb[c * 64 + 16 * w + quad * 4 + r];

    float   Dacc = 0.f;
    floatx4 oacc[4];
#pragma unroll
    for (int a = 0; a < 4; ++a) oacc[a] = (floatx4){0.f, 0.f, 0.f, 0.f};

    // bpermute sources for the P->A-fragment exchange (see below)
    int sA = l15 + ((lane & 16) ? 32 : 0);   // lane (l15, 2*(q&1))
    int sB = sA + 16;                        // lane (l15, 2*(q&1)+1)
    bool qhi = (lane >= 32);                 // q>>1

    for (int half = 0; half < 2; ++half) {
        int ck = half ? cm : c;
        __syncthreads();              // prev-half K/V LDS reads complete

        {   // stage K (L2-normalized, hi-only RNE): 4 threads/row, 16 dims each
            int r = tid >> 2, s = tid & 3;
            int trow = stb[ck * 64 + r];
            if (s == 0) tk[r] = trow;
            const float4* k4 = (const float4*)(qkb + (size_t)trow * DIM + s * 16);
            float xs[16];
            *(float4*)&xs[0]  = k4[0];
            *(float4*)&xs[4]  = k4[1];
            *(float4*)&xs[8]  = k4[2];
            *(float4*)&xs[12] = k4[3];
            float ss = 0.f;
#pragma unroll
            for (int u = 0; u < 16; ++u) ss += xs[u] * xs[u];
            ss += __shfl_xor(ss, 1);
            ss += __shfl_xor(ss, 2);
            float sc = 1.0f / fmaxf(sqrtf(ss), 1e-12f);
#pragma unroll
            for (int u = 0; u < 16; ++u) xs[u] *= sc;
            hi16_store_cvt(xs, &Khi[r * SB + s * 16]);
        }
        {   // stage V TRANSPOSED (hi-only RNE): thread = dim lane, keys w*16..+15
            float xs[16];
#pragma unroll
            for (int u = 0; u < 16; ++u) {
                int trow = stb[ck * 64 + w * 16 + u];     // wave-uniform
                xs[u] = vb[(size_t)trow * DIM + lane];    // coalesced 256B row
            }
            hi16_store_cvt(xs, &Vhi[lane * SB + w * 16]);
        }
        __syncthreads();              // K, Vt, tk staged

        // dots SWAPPED: dt[jt] = K_tile(jt) x Q  ->  C: row=key(quad*4+r),
        // col=query(l15). One MFMA per (kb,jt) -- Q hi-only.
        floatx4 dt[4];
#pragma unroll
        for (int jt = 0; jt < 4; ++jt) dt[jt] = (floatx4){0.f, 0.f, 0.f, 0.f};
#pragma unroll
        for (int kb = 0; kb < 2; ++kb) {
#pragma unroll
            for (int jt = 0; jt < 4; ++jt) {
                short8 kf = *(const short8*)&Khi[(16 * jt + l15) * SB + kb * 32 + quad * 8];
                dt[jt] = __builtin_amdgcn_mfma_f32_16x16x32_bf16(kf, qH[kb], dt[jt], 0, 0, 0);
            }
        }
        // NO barrier: P stays in registers from here on.

        // mask + exp + pack: lane holds P[key=16jt+quad*4+r][query=qt]
        unsigned U[8];                 // U[2*jt+s] = bf16 pair (r=2s, 2s+1)
#pragma unroll
        for (int jt = 0; jt < 4; ++jt) {
            int4 tkq = *(const int4*)&tk[16 * jt + quad * 4];
            float p0 = (qt == tkq.x) ? 0.f : __expf(dt[jt][0] * 0.125f);
            float p1 = (qt == tkq.y) ? 0.f : __expf(dt[jt][1] * 0.125f);
            float p2 = (qt == tkq.z) ? 0.f : __expf(dt[jt][2] * 0.125f);
            float p3 = (qt == tkq.w) ? 0.f : __expf(dt[jt][3] * 0.125f);
            Dacc += (p0 + p1) + (p2 + p3);
            U[2*jt]     = pk_bf16(p0, p1);
            U[2*jt + 1] = pk_bf16(p2, p3);
        }

        // P -> A-fragment redistribution (in-register, within wave):
        // A needs lane(l15,q): keys kb*32 + q*8 + e. Source of key k:
        // jt=k>>4 (=2kb + q>>1), lane (l15, (k&15)>>2), r=k&3.
#pragma unroll
        for (int kb = 0; kb < 2; ++kb) {
            unsigned xA0 = (unsigned)__shfl((int)U[4*kb + 0], sA, 64);
            unsigned yA0 = (unsigned)__shfl((int)U[4*kb + 2], sA, 64);
            unsigned xA1 = (unsigned)__shfl((int)U[4*kb + 1], sA, 64);
            unsigned yA1 = (unsigned)__shfl((int)U[4*kb + 3], sA, 64);
            unsigned xB0 = (unsigned)__shfl((int)U[4*kb + 0], sB, 64);
            unsigned yB0 = (unsigned)__shfl((int)U[4*kb + 2], sB, 64);
            unsigned xB1 = (unsigned)__shfl((int)U[4*kb + 1], sB, 64);
            unsigned yB1 = (unsigned)__shfl((int)U[4*kb + 3], sB, 64);
            union { uint4 u; short8 s; } A;
            A.u.x = qhi ? yA0 : xA0;
            A.u.y = qhi ? yA1 : xA1;
            A.u.z = qhi ? yB0 : xB0;
            A.u.w = qhi ? yB1 : xB1;
#pragma unroll
            for (int a = 0; a < 4; ++a) {
                short8 bH = *(const short8*)&Vhi[(16 * a + l15) * SB + kb * 32 + quad * 8];
                oacc[a] = __builtin_amdgcn_mfma_f32_16x16x32_bf16(A.s, bH, oacc[a], 0, 0, 0);
            }
        }
    }

    // epilogue: O rows = quad*4+r (tokens tqr[r]), cols = dims 16a+l15.
    int h = c >> 6;
#pragma unroll
    for (int r = 0; r < 4; ++r) {
        int t = tqr[r];
        size_t rowb = ((size_t)(b * SEQ + t) * NHASH + h) * DIM;
#pragma unroll
        for (int a = 0; a < 4; ++a)
            Obuf[rowb + 16 * a + l15] = __float2half(oacc[a][r]);
    }
    // D: lane's Dacc is the partial rowsum for query qt over its key subset;
    // full sum = reduce across quads (lanes l15+16q).
    Dacc += __shfl_xor(Dacc, 16);
    Dacc += __shfl_xor(Dacc, 32);
    if (lane < 16) Dbuf[(size_t)(b * SEQ + qt) * NHASH + h] = Dacc;
}

// ---------------------------------------------------------------------------
// Kernel 4: out[b,t] = sum_h O_h / sum_h D_h -- streaming, fp16 numerator.
// ---------------------------------------------------------------------------
__global__ __launch_bounds__(256) void lsh_combine_tok(
    const __half* __restrict__ Obuf, const float* __restrict__ Dbuf,
    float* __restrict__ out)
{
    int gid = blockIdx.x * 256 + threadIdx.x;   // (b*4096+t)*16 + d4
    int d4 = gid & 15;
    int bt = gid >> 4;

    const __half* op = Obuf + (size_t)bt * (NHASH * DIM) + d4 * 4;
    const float*  dp = Dbuf + (size_t)bt * NHASH;

    float4 n = make_float4(0.f, 0.f, 0.f, 0.f);
    float den = 0.f;
#pragma unroll
    for (int h = 0; h < NHASH; ++h) {
        uint2 u = *(const uint2*)(op + h * DIM);
        __half2 p01 = *(__half2*)&u.x;
        __half2 p23 = *(__half2*)&u.y;
        float2 f01 = __half22float2(p01);
        float2 f23 = __half22float2(p23);
        den += dp[h];
        n.x += f01.x; n.y += f01.y; n.z += f23.x; n.w += f23.y;
    }
    float invd = 1.0f / den;
    float4 r; r.x = n.x*invd; r.y = n.y*invd; r.z = n.z*invd; r.w = n.w*invd;
    ((float4*)out)[gid] = r;
}

extern "C" void kernel_launch(void* const* d_in, const int* in_sizes, int n_in,
                              void* d_out, int out_size, void* d_ws, size_t ws_size,
                              hipStream_t stream)
{
    const float* qk  = (const float*)d_in[0];
    const float* v   = (const float*)d_in[1];
    const float* rot = (const float*)d_in[2];
    float* out = (float*)d_out;

    char* w = (char*)d_ws;
    // workspace layout (73.2 MB):
    //   [0, 2MB)          buckets : int[16*8*4096]
    //   [2, 4MB)          st      : int[16*8*4096]
    //   [4MB, +67.1MB)    Obuf    : fp16[16*4096*8*64]  (token-major, h inner)
    //   then              Dbuf    : fp32[16*4096*8]
    int*    buckets = (int*)(w);
    int*    st      = (int*)(w + 2097152);
    __half* Obuf    = (__half*)(w + 4194304);
    float*  Dbuf    = (float*)(w + 4194304 + 67108864);

    lsh_hash_kernel<<<1024, 256, 0, stream>>>(qk, rot, buckets);
    lsh_sort_kernel<<<128, 256, 0, stream>>>(buckets, st);
    lsh_attn_kernel<<<8192, 256, 0, stream>>>(qk, v, st, Obuf, Dbuf);
    lsh_combine_tok<<<4096, 256, 0, stream>>>(Obuf, Dbuf, out);
}

// Round 9
// 192.843 us; speedup vs baseline: 1.2096x; 1.0294x over previous
//
#include <hip/hip_runtime.h>
#include <hip/hip_fp16.h>
#include <hip/hip_bf16.h>

#define BATCH  16
#define SEQ    4096
#define DIM    64
#define NHASH  8
#define NCHUNK 512   // chunks per batch row (NHASH * SEQ / 64)
#define SB     72    // bf16 LDS row stride: 72*2=144 B, 16B-aligned for b128

typedef __attribute__((ext_vector_type(8))) short short8;   // 8 bf16 (4 VGPR)
typedef __attribute__((ext_vector_type(4))) float floatx4;  // MFMA C/D

// 16 fp32 -> 16 bf16 via paired HW cvt (v_cvt_pk_bf16_f32, RNE)
__device__ __forceinline__ void hi16_store_cvt(const float* xs, short* dst) {
    union { __hip_bfloat162 h2[8]; uint4 u4[2]; } U;
#pragma unroll
    for (int u = 0; u < 8; ++u)
        U.h2[u] = __float22bfloat162_rn(make_float2(xs[2*u], xs[2*u + 1]));
    *(uint4*)(dst)     = U.u4[0];
    *(uint4*)(dst + 8) = U.u4[1];
}
__device__ __forceinline__ unsigned pk_bf16(float a, float b) {
    union { __hip_bfloat162 h2; unsigned u; } U;
    U.h2 = __float22bfloat162_rn(make_float2(a, b));
    return U.u;
}

__device__ __forceinline__ void argmax_store(
    const float* a, int gid, int h, int* __restrict__ buckets)
{
    float best = a[0]; int bi = 0;
#pragma unroll
    for (int i = 1; i < 32; ++i) { if (a[i] > best) { best = a[i]; bi = i; } }
#pragma unroll
    for (int i = 0; i < 32; ++i) { float nv = -a[i]; if (nv > best) { best = nv; bi = i + 32; } }
    int b = gid >> 12, t = gid & 4095;
    buckets[((size_t)b * NHASH + h) * SEQ + t] = bi;
}

// ---------------------------------------------------------------------------
// Kernel 1: LSH hashing (R17 config: grid 1024, 2 h'/block, 16 KB rot LDS,
// 4 blocks/CU, no spill). Proven at the ~201 us total; near its VALU floor.
// ---------------------------------------------------------------------------
__global__ __launch_bounds__(256, 4) void lsh_hash_kernel(
    const float* __restrict__ qk, const float* __restrict__ rot,
    int* __restrict__ buckets)
{
    __shared__ float rs[64 * 64];      // [f][h'][i] = f*64 + hh*32 + i (16 KB)
    int tid = threadIdx.x;
    int tb   = blockIdx.x >> 2;        // 256-token tile
    int hsel = blockIdx.x & 3;         // h pair: h = hsel*2 + hh

    {   // stage rot slice: 1024 float4, 4 per thread, coalesced
        const float4* rg = (const float4*)rot;
#pragma unroll
        for (int j = 0; j < 4; ++j) {
            int idx4 = j * 256 + tid;
            int f = idx4 >> 4, r4 = idx4 & 15;     // r4 = hh*8 + i4
            ((float4*)rs)[idx4] = rg[f * 64 + hsel * 16 + r4];
        }
    }
    __syncthreads();

    int tt = tid & 127;
    int hh = tid >> 7;                 // 0/1, wave-uniform
    int gid0 = tb * 256 + tt;
    int gid1 = gid0 + 128;
    const float* q0 = qk + (size_t)gid0 * DIM;
    const float* q1 = qk + (size_t)gid1 * DIM;
    const float* rbase = rs + hh * 32;

    float a0[32], a1[32];
#pragma unroll
    for (int i = 0; i < 32; ++i) { a0[i] = 0.f; a1[i] = 0.f; }

#pragma unroll 1
    for (int ft = 0; ft < 8; ++ft) {
        float qa[8], qb[8];
        *(float4*)&qa[0] = *(const float4*)(q0 + ft * 8);
        *(float4*)&qa[4] = *(const float4*)(q0 + ft * 8 + 4);
        *(float4*)&qb[0] = *(const float4*)(q1 + ft * 8);
        *(float4*)&qb[4] = *(const float4*)(q1 + ft * 8 + 4);
#pragma unroll
        for (int f8 = 0; f8 < 8; ++f8) {
            const float* rp = rbase + (ft * 8 + f8) * 64;
            float x0 = qa[f8], x1 = qb[f8];
#pragma unroll
            for (int i = 0; i < 32; ++i) {
                float r = rp[i];
                a0[i] = fmaf(x0, r, a0[i]);
                a1[i] = fmaf(x1, r, a1[i]);
            }
        }
    }

    int h = hsel * 2 + hh;
    argmax_store(a0, gid0, h, buckets);
    argmax_store(a1, gid1, h, buckets);
}

// ---------------------------------------------------------------------------
// Kernel 2: stable counting sort per (b,h), 4-wave (unchanged).
// ---------------------------------------------------------------------------
__global__ __launch_bounds__(256) void lsh_sort_kernel(
    const int* __restrict__ buckets, int* __restrict__ st)
{
    __shared__ int hist[256 * 65];
    __shared__ int seg[256];
    __shared__ int base[64];

    int bh = blockIdx.x;
    int tid = threadIdx.x;
    int w = tid >> 6, lane = tid & 63;

    for (int i = tid; i < 256 * 65; i += 256) hist[i] = 0;

    int myb[16];
    {
        const int4* bp4 = (const int4*)(buckets + (size_t)bh * SEQ);
#pragma unroll
        for (int u4 = 0; u4 < 4; ++u4) {
            int4 bb = bp4[tid * 4 + u4];
            myb[u4*4+0] = bb.x; myb[u4*4+1] = bb.y;
            myb[u4*4+2] = bb.z; myb[u4*4+3] = bb.w;
        }
    }
    __syncthreads();
    int* hrow = &hist[tid * 65];
#pragma unroll
    for (int u = 0; u < 16; ++u) hrow[myb[u]] += 1;
    __syncthreads();

    {
        int run = 0;
        for (int tp = 0; tp < 64; ++tp) {
            int idx = (w * 64 + tp) * 65 + lane;
            int c0 = hist[idx];
            hist[idx] = run;
            run += c0;
        }
        seg[w * 64 + lane] = run;
    }
    __syncthreads();
    if (tid < 64) {
        int s0 = seg[lane], s1 = seg[64 + lane], s2 = seg[128 + lane], s3 = seg[192 + lane];
        seg[lane] = 0; seg[64 + lane] = s0;
        seg[128 + lane] = s0 + s1; seg[192 + lane] = s0 + s1 + s2;
        int tot = s0 + s1 + s2 + s3;
        int x = tot;
#pragma unroll
        for (int d = 1; d < 64; d <<= 1) {
            int y = __shfl_up(x, d, 64);
            if (lane >= d) x += y;
        }
        base[lane] = x - tot;
    }
    __syncthreads();

    int* op = st + (size_t)bh * SEQ;
#pragma unroll
    for (int u = 0; u < 16; ++u) {
        int bb = myb[u];
        int local = hrow[bb];
        hrow[bb] = local + 1;
        int pos = base[bb] + seg[w * 64 + bb] + local;
        op[pos] = tid * 16 + u;
    }
}

// ---------------------------------------------------------------------------
// Kernel 3: MFMA attention. R19: single-variable occupancy probe, 5 -> 6
// blocks/CU (pad 10 KB -> 8 KB; 26.9 KB/block). R18 diagnosis: no pipe >51%
// (VALU 50, MFMA 8, HBM 15) = latency/barrier-drain bound -- 4 barriers per
// block each preceded by a full vmcnt drain of the gather loads; 20 resident
// waves/CU can't fill the stall. 6 blocks = 24 waves/CU (+20%).
// Pre-committed failure read: FETCH > 100 MB => L2 cliff (R12) tipped,
// revert to 5 and treat attn as structurally converged.
// Keeps: swapped QK^T in-register P, XCD swizzle, fp16 Obuf, cvt_pk staging.
// ---------------------------------------------------------------------------
__global__ __launch_bounds__(256, 6) void lsh_attn_kernel(
    const float* __restrict__ qk, const float* __restrict__ v,
    const int* __restrict__ st, __half* __restrict__ Obuf, float* __restrict__ Dbuf)
{
    __shared__ short Khi[64 * SB];     // staged K-hi (L2-normalized)
    __shared__ short Vhi[64 * SB];     // transposed: [dim][key], hi only
    __shared__ int   tk[64];
    __shared__ float lds_pad[2048];    // 8 KB occupancy cap: 26.9 KB -> 6 blk/CU

    int tid  = threadIdx.x;
    {   // volatile touch so the pad allocation can't be eliminated
        volatile float* vp = lds_pad;
        vp[tid] = 0.f;
    }
    int lane = tid & 63;
    int w    = tid >> 6;          // wave id = query-strip / V key-group
    int quad = lane >> 4;
    int l15  = lane & 15;

    // XCD-aware chunk assignment: XCD x processes chunks [x*1024, x*1024+1024)
    // = 2 whole batches sequentially (8192 = 8 XCDs * 1024, bijective).
    int B  = blockIdx.x;
    int bc = ((B & 7) << 10) | (B >> 3);
    int b = bc >> 9, c = bc & (NCHUNK - 1);
    int cm = (c + NCHUNK - 1) & (NCHUNK - 1);

    const int*   stb = st + (size_t)b * (NHASH * SEQ);
    const float* qkb = qk + (size_t)b * SEQ * DIM;
    const float* vb  = v  + (size_t)b * SEQ * DIM;

    // ---- Q fragment (hi-only RNE) in registers; qt = this lane's Q token ----
    short8 qH[2];
    int qt;
    {
        qt = stb[c * 64 + 16 * w + l15];
        const float* qp = qkb + (size_t)qt * DIM + 8 * quad;
#pragma unroll
        for (int kb = 0; kb < 2; ++kb) {
            float xs[8];
            *(float4*)&xs[0] = *(const float4*)(qp + 32 * kb);
            *(float4*)&xs[4] = *(const float4*)(qp + 32 * kb + 4);
            union { __hip_bfloat162 h2[4]; short8 s; } Uq;
#pragma unroll
            for (int u = 0; u < 4; ++u)
                Uq.h2[u] = __float22bfloat162_rn(make_float2(xs[2*u], xs[2*u + 1]));
            qH[kb] = Uq.s;
        }
    }
    // epilogue row-ids for this lane's O fragment rows (quad*4+r)
    int tqr[4];
#pragma unroll
    for (int r = 0; r < 4; ++r) tqr[r] = stb[c * 64 + 16 * w + quad * 4 + r];

    float   Dacc = 0.f;
    floatx4 oacc[4];
#pragma unroll
    for (int a = 0; a < 4; ++a) oacc[a] = (floatx4){0.f, 0.f, 0.f, 0.f};

    // bpermute sources for the P->A-fragment exchange (see below)
    int sA = l15 + ((lane & 16) ? 32 : 0);   // lane (l15, 2*(q&1))
    int sB = sA + 16;                        // lane (l15, 2*(q&1)+1)
    bool qhi = (lane >= 32);                 // q>>1

    for (int half = 0; half < 2; ++half) {
        int ck = half ? cm : c;
        __syncthreads();              // prev-half K/V LDS reads complete

        {   // stage K (L2-normalized, hi-only RNE): 4 threads/row, 16 dims each
            int r = tid >> 2, s = tid & 3;
            int trow = stb[ck * 64 + r];
            if (s == 0) tk[r] = trow;
            const float4* k4 = (const float4*)(qkb + (size_t)trow * DIM + s * 16);
            float xs[16];
            *(float4*)&xs[0]  = k4[0];
            *(float4*)&xs[4]  = k4[1];
            *(float4*)&xs[8]  = k4[2];
            *(float4*)&xs[12] = k4[3];
            float ss = 0.f;
#pragma unroll
            for (int u = 0; u < 16; ++u) ss += xs[u] * xs[u];
            ss += __shfl_xor(ss, 1);
            ss += __shfl_xor(ss, 2);
            float sc = 1.0f / fmaxf(sqrtf(ss), 1e-12f);
#pragma unroll
            for (int u = 0; u < 16; ++u) xs[u] *= sc;
            hi16_store_cvt(xs, &Khi[r * SB + s * 16]);
        }
        {   // stage V TRANSPOSED (hi-only RNE): thread = dim lane, keys w*16..+15
            float xs[16];
#pragma unroll
            for (int u = 0; u < 16; ++u) {
                int trow = stb[ck * 64 + w * 16 + u];     // wave-uniform
                xs[u] = vb[(size_t)trow * DIM + lane];    // coalesced 256B row
            }
            hi16_store_cvt(xs, &Vhi[lane * SB + w * 16]);
        }
        __syncthreads();              // K, Vt, tk staged

        // dots SWAPPED: dt[jt] = K_tile(jt) x Q  ->  C: row=key(quad*4+r),
        // col=query(l15). One MFMA per (kb,jt) -- Q hi-only.
        floatx4 dt[4];
#pragma unroll
        for (int jt = 0; jt < 4; ++jt) dt[jt] = (floatx4){0.f, 0.f, 0.f, 0.f};
#pragma unroll
        for (int kb = 0; kb < 2; ++kb) {
#pragma unroll
            for (int jt = 0; jt < 4; ++jt) {
                short8 kf = *(const short8*)&Khi[(16 * jt + l15) * SB + kb * 32 + quad * 8];
                dt[jt] = __builtin_amdgcn_mfma_f32_16x16x32_bf16(kf, qH[kb], dt[jt], 0, 0, 0);
            }
        }
        // NO barrier: P stays in registers from here on.

        // mask + exp + pack: lane holds P[key=16jt+quad*4+r][query=qt]
        unsigned U[8];                 // U[2*jt+s] = bf16 pair (r=2s, 2s+1)
#pragma unroll
        for (int jt = 0; jt < 4; ++jt) {
            int4 tkq = *(const int4*)&tk[16 * jt + quad * 4];
            float p0 = (qt == tkq.x) ? 0.f : __expf(dt[jt][0] * 0.125f);
            float p1 = (qt == tkq.y) ? 0.f : __expf(dt[jt][1] * 0.125f);
            float p2 = (qt == tkq.z) ? 0.f : __expf(dt[jt][2] * 0.125f);
            float p3 = (qt == tkq.w) ? 0.f : __expf(dt[jt][3] * 0.125f);
            Dacc += (p0 + p1) + (p2 + p3);
            U[2*jt]     = pk_bf16(p0, p1);
            U[2*jt + 1] = pk_bf16(p2, p3);
        }

        // P -> A-fragment redistribution (in-register, within wave):
        // A needs lane(l15,q): keys kb*32 + q*8 + e. Source of key k:
        // jt=k>>4 (=2kb + q>>1), lane (l15, (k&15)>>2), r=k&3.
#pragma unroll
        for (int kb = 0; kb < 2; ++kb) {
            unsigned xA0 = (unsigned)__shfl((int)U[4*kb + 0], sA, 64);
            unsigned yA0 = (unsigned)__shfl((int)U[4*kb + 2], sA, 64);
            unsigned xA1 = (unsigned)__shfl((int)U[4*kb + 1], sA, 64);
            unsigned yA1 = (unsigned)__shfl((int)U[4*kb + 3], sA, 64);
            unsigned xB0 = (unsigned)__shfl((int)U[4*kb + 0], sB, 64);
            unsigned yB0 = (unsigned)__shfl((int)U[4*kb + 2], sB, 64);
            unsigned xB1 = (unsigned)__shfl((int)U[4*kb + 1], sB, 64);
            unsigned yB1 = (unsigned)__shfl((int)U[4*kb + 3], sB, 64);
            union { uint4 u; short8 s; } A;
            A.u.x = qhi ? yA0 : xA0;
            A.u.y = qhi ? yA1 : xA1;
            A.u.z = qhi ? yB0 : xB0;
            A.u.w = qhi ? yB1 : xB1;
#pragma unroll
            for (int a = 0; a < 4; ++a) {
                short8 bH = *(const short8*)&Vhi[(16 * a + l15) * SB + kb * 32 + quad * 8];
                oacc[a] = __builtin_amdgcn_mfma_f32_16x16x32_bf16(A.s, bH, oacc[a], 0, 0, 0);
            }
        }
    }

    // epilogue: O rows = quad*4+r (tokens tqr[r]), cols = dims 16a+l15.
    int h = c >> 6;
#pragma unroll
    for (int r = 0; r < 4; ++r) {
        int t = tqr[r];
        size_t rowb = ((size_t)(b * SEQ + t) * NHASH + h) * DIM;
#pragma unroll
        for (int a = 0; a < 4; ++a)
            Obuf[rowb + 16 * a + l15] = __float2half(oacc[a][r]);
    }
    // D: lane's Dacc is the partial rowsum for query qt over its key subset;
    // full sum = reduce across quads (lanes l15+16q).
    Dacc += __shfl_xor(Dacc, 16);
    Dacc += __shfl_xor(Dacc, 32);
    if (lane < 16) Dbuf[(size_t)(b * SEQ + qt) * NHASH + h] = Dacc;
}

// ---------------------------------------------------------------------------
// Kernel 4: out[b,t] = sum_h O_h / sum_h D_h -- streaming, fp16 numerator.
// ---------------------------------------------------------------------------
__global__ __launch_bounds__(256) void lsh_combine_tok(
    const __half* __restrict__ Obuf, const float* __restrict__ Dbuf,
    float* __restrict__ out)
{
    int gid = blockIdx.x * 256 + threadIdx.x;   // (b*4096+t)*16 + d4
    int d4 = gid & 15;
    int bt = gid >> 4;

    const __half* op = Obuf + (size_t)bt * (NHASH * DIM) + d4 * 4;
    const float*  dp = Dbuf + (size_t)bt * NHASH;

    float4 n = make_float4(0.f, 0.f, 0.f, 0.f);
    float den = 0.f;
#pragma unroll
    for (int h = 0; h < NHASH; ++h) {
        uint2 u = *(const uint2*)(op + h * DIM);
        __half2 p01 = *(__half2*)&u.x;
        __half2 p23 = *(__half2*)&u.y;
        float2 f01 = __half22float2(p01);
        float2 f23 = __half22float2(p23);
        den += dp[h];
        n.x += f01.x; n.y += f01.y; n.z += f23.x; n.w += f23.y;
    }
    float invd = 1.0f / den;
    float4 r; r.x = n.x*invd; r.y = n.y*invd; r.z = n.z*invd; r.w = n.w*invd;
    ((float4*)out)[gid] = r;
}

extern "C" void kernel_launch(void* const* d_in, const int* in_sizes, int n_in,
                              void* d_out, int out_size, void* d_ws, size_t ws_size,
                              hipStream_t stream)
{
    const float* qk  = (const float*)d_in[0];
    const float* v   = (const float*)d_in[1];
    const float* rot = (const float*)d_in[2];
    float* out = (float*)d_out;

    char* w = (char*)d_ws;
    // workspace layout (73.2 MB):
    //   [0, 2MB)          buckets : int[16*8*4096]
    //   [2, 4MB)          st      : int[16*8*4096]
    //   [4MB, +67.1MB)    Obuf    : fp16[16*4096*8*64]  (token-major, h inner)
    //   then              Dbuf    : fp32[16*4096*8]
    int*    buckets = (int*)(w);
    int*    st      = (int*)(w + 2097152);
    __half* Obuf    = (__half*)(w + 4194304);
    float*  Dbuf    = (float*)(w + 4194304 + 67108864);

    lsh_hash_kernel<<<1024, 256, 0, stream>>>(qk, rot, buckets);
    lsh_sort_kernel<<<128, 256, 0, stream>>>(buckets, st);
    lsh_attn_kernel<<<8192, 256, 0, stream>>>(qk, v, st, Obuf, Dbuf);
    lsh_combine_tok<<<4096, 256, 0, stream>>>(Obuf, Dbuf, out);
}